// Round 1
// 183.256 us; speedup vs baseline: 1.3436x; 1.3436x over previous
//
#include <hip/hip_runtime.h>

typedef unsigned short u16;
typedef __attribute__((ext_vector_type(8))) short short8;
typedef __attribute__((ext_vector_type(4))) float float4v;

__device__ __forceinline__ u16 f2bf(float f) {
    unsigned u = __float_as_uint(f);
    u += 0x7FFFu + ((u >> 16) & 1u);   // RNE
    return (u16)(u >> 16);
}
__device__ __forceinline__ float bf2f(u16 u) {
    return __uint_as_float(((unsigned)u) << 16);
}

// ---------------------------------------------------------------------------
// Module .bss intermediates (d_ws proved unreliable in earlier rounds).
// ---------------------------------------------------------------------------
__device__ float g_maxout[4 * 32 * 4096];   // 2 MB fp32
__device__ float g_q[16384];
__device__ float g_qmean[16384];
__device__ float g_lit[128];
__device__ float g_sigfac[16384];
__device__ u16   g_Kw_bf[65536];            // K_w  bf16 [256 o][256 c]
__device__ u16   g_KSAw_bf[16384];          // KSA_w bf16 [32 o][512 c]
__device__ u16   g_Kx[4 * 256 * 16384];     // Kx bf16, 33.5 MB

// Zero lit + convert both weight matrices to bf16.
__global__ __launch_bounds__(256) void prep_kernel(
    const float* __restrict__ Kw, const float* __restrict__ KSAw)
{
    const int idx = blockIdx.x * 256 + threadIdx.x;
    if (idx < 128) g_lit[idx] = 0.f;
    if (idx < 65536) g_Kw_bf[idx] = f2bf(Kw[idx]);
    if (idx < 16384) g_KSAw_bf[idx] = f2bf(KSAw[idx]);
}

// ---------------------------------------------------------------------------
// Deep conv via MFMA: maxout[b][o][p] = sum_c KSA_w[o][c]*deep[b][c][p]+bias
// M=32, K=512, N=4096 per batch. A staged to LDS ONCE (32 KB), distance-2
// register prefetch on B, channel max/mean (qstats) fused into the epilogue.
// ---------------------------------------------------------------------------
__global__ __launch_bounds__(256) void gemm_deep(
    const float* __restrict__ Bias, const float* __restrict__ X)
{
    __shared__ u16 As[16384];                 // 32 KB: full KSA_w bf16 [32][512]
    const int t = threadIdx.x;
    const int wave = t >> 6, lane = t & 63;
    const int quad = lane >> 4, n16 = lane & 15;
    const int b = blockIdx.y;
    const int p = blockIdx.x * 64 + wave * 16 + n16;
    const float* Xb = X + ((long long)b << 21) + p;

    // Stage A once: per step, 256 threads cover a contiguous 4 KB (conflict-free).
#pragma unroll
    for (int c = 0; c < 8; c++) {
        const int idx = (c << 8) + t;         // 16B chunk id, contiguous per inst
        *(short8*)(As + idx * 8) = *(const short8*)(g_KSAw_bf + idx * 8);
    }

    float breg[2][8];
#pragma unroll
    for (int j = 0; j < 8; j++) breg[0][j] = Xb[((quad << 3) + j) << 12];
#pragma unroll
    for (int j = 0; j < 8; j++) breg[1][j] = Xb[(32 + (quad << 3) + j) << 12];

    __syncthreads();

    float4v acc[2];
#pragma unroll
    for (int i = 0; i < 2; i++) acc[i] = (float4v){0.f, 0.f, 0.f, 0.f};

#pragma unroll
    for (int kb = 0; kb < 16; kb++) {
        const int cur = kb & 1;
        short8 bfrag;
#pragma unroll
        for (int j = 0; j < 8; j++) bfrag[j] = (short)f2bf(breg[cur][j]);
        if (kb < 14) {                         // distance-2 prefetch into same slot
            const float* xp = Xb + (((kb + 2) << 5) << 12);
#pragma unroll
            for (int j = 0; j < 8; j++) breg[cur][j] = xp[((quad << 3) + j) << 12];
        }
        const u16* ap = As + n16 * 512 + kb * 32 + quad * 8;
#pragma unroll
        for (int ot = 0; ot < 2; ot++) {
            const short8 afrag = *(const short8*)(ap + ot * 8192);
            acc[ot] = __builtin_amdgcn_mfma_f32_16x16x32_bf16(afrag, bfrag, acc[ot], 0, 0, 0);
        }
    }

    // Epilogue: write maxout + fused qstats (channel max / mean per column).
    float mx = -3.4e38f, sm = 0.f;
#pragma unroll
    for (int ot = 0; ot < 2; ot++) {
#pragma unroll
        for (int r = 0; r < 4; r++) {
            const int o = ot * 16 + quad * 4 + r;
            const float v = acc[ot][r] + Bias[o];
            g_maxout[((b * 32 + o) << 12) + p] = v;
            mx = fmaxf(mx, v);
            sm += v;
        }
    }
    // reduce across the 4 quads holding this column (lanes ^16, ^32)
    mx = fmaxf(mx, __shfl_xor(mx, 16, 64));
    sm += __shfl_xor(sm, 16, 64);
    mx = fmaxf(mx, __shfl_xor(mx, 32, 64));
    sm += __shfl_xor(sm, 32, 64);
    if (quad == 0) {
        g_q[(b << 12) + p] = mx;
        g_qmean[(b << 12) + p] = sm * (1.f / 32.f);
    }
}

// lit[b][l] = (1/4096) * sum_i q[b][i] * flat[b][i*32+l]
__global__ __launch_bounds__(256) void lit_kernel()
{
    const int b = blockIdx.y;
    const int f0 = blockIdx.x * 8192;
    const int t = threadIdx.x;
    const float* mo = g_maxout + (b << 17);
    const float* qb = g_q + (b << 12);
    float acc = 0.f;
#pragma unroll
    for (int it = 0; it < 32; it++) {
        const int f = f0 + it * 256 + t;
        acc += qb[f >> 5] * mo[f];
    }
    __shared__ float red[256];
    red[t] = acc;
    __syncthreads();
    if (t < 32) {
        float s = 0.f;
#pragma unroll
        for (int k = 0; k < 8; k++) s += red[t + k * 32];
        atomicAdd(&g_lit[b * 32 + t], s * (1.f / 4096.f));
    }
}

// re_score -> out tail (fp32); sigfac = 1 + sigmoid(re)
__global__ __launch_bounds__(256) void rescore_kernel(float* __restrict__ out_re)
{
    const int idx = blockIdx.x * 256 + threadIdx.x;  // 16384
    const int b = idx >> 12, p = idx & 4095;
    const float* mo = g_maxout + (b << 17) + p;
    const float* lb = g_lit + b * 32;
    float r = 0.f;
#pragma unroll
    for (int j = 0; j < 32; j++) r += lb[j] * mo[j << 12];
    out_re[idx] = r;
    g_sigfac[idx] = 1.f + 1.f / (1.f + __expf(-r));
}

// ---------------------------------------------------------------------------
// Shallow conv as fat GEMM: Kx[b][o][s] = sum_c K_w[o][c]*shallow[b][c][s]+b.
// M=256, K=256, N=16384/batch. Double-buffered 16 KB LDS A-tile per K-step,
// distance-2 B register prefetch, issue-early/write-late A staging, one
// barrier per K-step so all load latency hides under the 16-MFMA block.
// ---------------------------------------------------------------------------
__global__ __launch_bounds__(256) void gemm_kx(
    const float* __restrict__ Bias, const float* __restrict__ X)
{
    __shared__ u16 As[2][8192];               // 2 x 16 KB: [256 rows][32 k] bf16
    const int t = threadIdx.x;
    const int wave = t >> 6, lane = t & 63;
    const int quad = lane >> 4, n16 = lane & 15;
    const int b = blockIdx.y;
    const int p = blockIdx.x * 64 + wave * 16 + n16;
    const float* Xb = X + ((long long)b << 22) + p;

    // A-staging addressing: wave covers rows [wave*64, wave*64+64), 4 insts of
    // 1 KB each; lane i covers row wave*64+s*16+(i>>2), 16B chunk (i&3).
    const int arow = wave * 64 + (lane >> 2);
    const u16* ag = g_Kw_bf + arow * 256 + (lane & 3) * 8;   // + s*4096 + kb*32
    const int alw = wave * 2048 + lane * 8;                   // short idx in buf, + s*512

    float breg[2][8];
    float4v acc[16];
#pragma unroll
    for (int i = 0; i < 16; i++) acc[i] = (float4v){0.f, 0.f, 0.f, 0.f};

    // prologue: B(0), B(1) into regs; A(0) into LDS buf0
#pragma unroll
    for (int j = 0; j < 8; j++) breg[0][j] = Xb[((quad << 3) + j) << 14];
#pragma unroll
    for (int j = 0; j < 8; j++) breg[1][j] = Xb[(32 + (quad << 3) + j) << 14];
    {
        short8 areg[4];
#pragma unroll
        for (int s = 0; s < 4; s++) areg[s] = *(const short8*)(ag + s * 4096);
#pragma unroll
        for (int s = 0; s < 4; s++) *(short8*)(&As[0][alw + s * 512]) = areg[s];
    }
    __syncthreads();

#pragma unroll
    for (int kb = 0; kb < 8; kb++) {
        const int cur = kb & 1;
        short8 bfrag;
#pragma unroll
        for (int j = 0; j < 8; j++) bfrag[j] = (short)f2bf(breg[cur][j]);

        short8 areg[4];
        if (kb < 6) {                          // distance-2 B prefetch (same slot)
            const float* xp = Xb + (((kb + 2) << 5) << 14);
#pragma unroll
            for (int j = 0; j < 8; j++) breg[cur][j] = xp[((quad << 3) + j) << 14];
        }
        if (kb < 7) {                          // issue A(kb+1) loads early
#pragma unroll
            for (int s = 0; s < 4; s++)
                areg[s] = *(const short8*)(ag + (kb + 1) * 32 + s * 4096);
        }

        const u16* ap = &As[cur][n16 * 32 + quad * 8];
#pragma unroll
        for (int ot = 0; ot < 16; ot++) {
            const short8 afrag = *(const short8*)(ap + ot * 512);
            acc[ot] = __builtin_amdgcn_mfma_f32_16x16x32_bf16(afrag, bfrag, acc[ot], 0, 0, 0);
        }

        if (kb < 7) {                          // write-late into the other buffer
#pragma unroll
            for (int s = 0; s < 4; s++)
                *(short8*)(&As[cur ^ 1][alw + s * 512]) = areg[s];
        }
        __syncthreads();
    }

    // C/D: col(p)=n16 (this lane's p), row(o)=ot*16+quad*4+r
    u16* kxb = g_Kx + (((long long)b << 8) << 14);
#pragma unroll
    for (int ot = 0; ot < 16; ot++) {
#pragma unroll
        for (int r = 0; r < 4; r++) {
            const int o = ot * 16 + quad * 4 + r;
            kxb[(o << 14) + p] = f2bf(acc[ot][r] + Bias[o]);
        }
    }
}

// ---------------------------------------------------------------------------
// Windowed softmax attention from bf16 Kx. Block = (b,o) fixed, 4 output rows
// (256 outputs). Input rows staged coalesced into LDS with zero-padded
// borders; window reads are 2-way-conflict (free) LDS loads.
// ---------------------------------------------------------------------------
__global__ __launch_bounds__(256) void att_window(float* __restrict__ out)
{
    __shared__ float tile[9][132];             // rows y0..y0+8, col x stored at x+1
    const int t = threadIdx.x;
    const int o = blockIdx.y, b = blockIdx.z;
    const int ph0 = blockIdx.x << 2;           // 4 output rows per block
    const int y0 = (ph0 << 1) - 1;
    const u16* kxp = g_Kx + ((((long long)b << 8) + o) << 14);

    if (t < 18) tile[t >> 1][(t & 1) ? 129 : 0] = 0.f;   // left/right pad cols
#pragma unroll
    for (int k = 0; k < 5; k++) {
        const int e = (k << 8) + t;            // 0..1151
        if (e < 1152) {
            const int r = e >> 7, x = e & 127;
            const int y = y0 + r;
            tile[r][x + 1] = (y >= 0 && y < 128) ? bf2f(kxp[(y << 7) + x]) : 0.f;
        }
    }
    __syncthreads();

    const int p = (blockIdx.x << 8) + t;       // output index 0..4095
    const int pw = t & 63;
    const int rloc = (t >> 6) << 1;            // tile row of y=2*ph-1
    const float m = g_qmean[(b << 12) + p];
    const float sf = g_sigfac[(b << 12) + p];

    float v[9];
#pragma unroll
    for (int ki = 0; ki < 3; ++ki)
#pragma unroll
        for (int kj = 0; kj < 3; ++kj)
            v[ki * 3 + kj] = tile[rloc + ki][(pw << 1) + kj];

    float mx = -3.4e38f;
#pragma unroll
    for (int k = 0; k < 9; ++k) mx = fmaxf(mx, m * v[k]);
    float s = 0.f, a = 0.f;
#pragma unroll
    for (int k = 0; k < 9; ++k) {
        const float e = __expf(m * v[k] - mx);
        s += e;
        a += e * v[k];
    }
    out[((((long long)b << 8) + o) << 12) + p] = (a / s) * sf;
}

extern "C" void kernel_launch(void* const* d_in, const int* in_sizes, int n_in,
                              void* d_out, int out_size, void* d_ws, size_t ws_size,
                              hipStream_t stream) {
    const float *shallow = 0, *deep = 0, *K_w = 0, *K_b = 0, *KSA_w = 0, *KSA_b = 0;
    for (int i = 0; i < n_in; ++i) {
        switch (in_sizes[i]) {
            case 16777216: shallow = (const float*)d_in[i]; break;
            case 8388608:  deep    = (const float*)d_in[i]; break;
            case 65536:    K_w     = (const float*)d_in[i]; break;
            case 256:      K_b     = (const float*)d_in[i]; break;
            case 16384:    KSA_w   = (const float*)d_in[i]; break;
            case 32:       KSA_b   = (const float*)d_in[i]; break;
        }
    }
    float* out = (float*)d_out;   // FP32: 4194304 att + 16384 re_score

    // 0) zero lit + bf16-convert weight matrices
    prep_kernel<<<320, 256, 0, stream>>>(K_w, KSA_w);
    // 1) deep conv (MFMA, LDS-staged A) + fused channel max/mean
    gemm_deep<<<dim3(64, 4), 256, 0, stream>>>(KSA_b, deep);
    // 2) lit (channel-scrambled, /hw)
    lit_kernel<<<dim3(16, 4), 256, 0, stream>>>();
    // 3) re_score (fp32 -> out tail) + sigmoid factor
    rescore_kernel<<<64, 256, 0, stream>>>(out + 4194304);
    // 4) shallow conv as pipelined LDS-tiled GEMM -> Kx bf16 (.bss)
    gemm_kx<<<dim3(256, 4), 256, 0, stream>>>(K_b, shallow);
    // 5) windowed softmax attention + sig scaling (LDS-staged window)
    att_window<<<dim3(16, 256, 4), 256, 0, stream>>>(out);
}